// Round 1
// baseline (490.878 us; speedup 1.0000x reference)
//
#include <hip/hip_runtime.h>

// HealEncoding: 4-level HEALPix multires hash-ish encoding.
// params        [4, 792, 2]  f32   (25 KB -> LDS)
// pixel_latlon  [4, B, 2]    f32
// neigh_latlon  [4, 8B, 2]   f32   (index i = j*B + b)
// pixel_index   [4, B]       i32
// neigh_index   [4, 8, B]    i32   (-1 = missing -> contributes 0)
// out           [B, 8]       f32   out[b, 4*f + l] = res[l][b][f]

#define NLEV 4
#define MAXSZ 792
#define TABSZ (NLEV * MAXSZ * 2)   // 6336 floats = 25344 B

__global__ __launch_bounds__(256) void heal_encoding_kernel(
    const float* __restrict__ params,
    const float* __restrict__ pixel_latlon,
    const float* __restrict__ neigh_latlon,
    const int*   __restrict__ pixel_index,
    const int*   __restrict__ neigh_index,
    float* __restrict__ out,
    int B)
{
    __shared__ float sparams[TABSZ];
    for (int i = threadIdx.x; i < TABSZ; i += 256)
        sparams[i] = params[i];
    __syncthreads();

    int b = blockIdx.x * 256 + threadIdx.x;
    if (b >= B) return;

    const float2* pll2 = (const float2*)pixel_latlon;
    const float2* nll2 = (const float2*)neigh_latlon;

    float res[8];

    #pragma unroll
    for (int l = 0; l < NLEV; ++l) {
        int pi = pixel_index[l * B + b];
        if (pi < 0) pi = 768;               // ref: -1 -> max(idx)+1 = 768
        float2 pll = pll2[l * B + b];

        float acc0 = 0.0f, acc1 = 0.0f;     // neighbor sum first (ref order)
        #pragma unroll
        for (int j = 0; j < 8; ++j) {
            int   ni  = neigh_index[(l * 8 + j) * B + b];
            float2 nll = nll2[(l * 8 + j) * B + b];
            float dphi = nll.y - pll.y;
            float dth  = nll.x - pll.x;
            float d    = sqrtf(dphi * dphi + dth * dth);
            if (ni >= 0) {                  // masked-out neighbors contribute exactly 0
                float w = 1.0f / d;
                acc0 += w * sparams[(l * MAXSZ + ni) * 2 + 0];
                acc1 += w * sparams[(l * MAXSZ + ni) * 2 + 1];
            }
        }
        // residual (my_reps) added after the neighbor sum, like the reference
        acc0 += sparams[(l * MAXSZ + pi) * 2 + 0];
        acc1 += sparams[(l * MAXSZ + pi) * 2 + 1];

        res[l]     = acc0;   // feature 0 -> columns 0..3
        res[4 + l] = acc1;   // feature 1 -> columns 4..7
    }

    float4* o = (float4*)(out + (size_t)b * 8);
    o[0] = make_float4(res[0], res[1], res[2], res[3]);
    o[1] = make_float4(res[4], res[5], res[6], res[7]);
}

extern "C" void kernel_launch(void* const* d_in, const int* in_sizes, int n_in,
                              void* d_out, int out_size, void* d_ws, size_t ws_size,
                              hipStream_t stream) {
    const float* params       = (const float*)d_in[0];
    const float* pixel_latlon = (const float*)d_in[1];
    const float* neigh_latlon = (const float*)d_in[2];
    const int*   pixel_index  = (const int*)d_in[3];
    const int*   neigh_index  = (const int*)d_in[4];
    float* out = (float*)d_out;

    int B = in_sizes[3] / NLEV;   // pixel_index has 4*B elements
    int blocks = (B + 255) / 256;
    heal_encoding_kernel<<<blocks, 256, 0, stream>>>(
        params, pixel_latlon, neigh_latlon, pixel_index, neigh_index, out, B);
}

// Round 2
// 483.363 us; speedup vs baseline: 1.0155x; 1.0155x over previous
//
#include <hip/hip_runtime.h>

// HealEncoding, 4 pixels per thread (vectorized int4/float4 streams).
// params        [4, 792, 2]  f32   (25 KB -> LDS)
// pixel_latlon  [4, B, 2]    f32
// neigh_latlon  [4, 8B, 2]   f32   (element i = j*B + b)
// pixel_index   [4, B]       i32
// neigh_index   [4, 8, B]    i32   (-1 = missing -> contributes 0)
// out           [B, 8]       f32   out[b, 4*f + l] = res[l][b][f]

#define NLEV 4
#define MAXSZ 792
#define TABSZ (NLEV * MAXSZ * 2)   // 6336 floats = 25344 B

__device__ __forceinline__ void accum_one(
    const float2* __restrict__ sp2, int lbase,
    int ni, float nth, float nph, float pth, float pph,
    float& a0, float& a1)
{
    float dth = nth - pth;
    float dph = nph - pph;
    float d = sqrtf(dth * dth + dph * dph);
    float w = (ni >= 0) ? (1.0f / d) : 0.0f;   // mask -> exactly 0, like ref
    int idx = (ni >= 0) ? ni : 0;              // keep LDS read uniform
    float2 rep = sp2[lbase + idx];
    a0 += w * rep.x;
    a1 += w * rep.y;
}

__global__ __launch_bounds__(256) void heal_encoding_kernel(
    const float* __restrict__ params,
    const float* __restrict__ pixel_latlon,
    const float* __restrict__ neigh_latlon,
    const int*   __restrict__ pixel_index,
    const int*   __restrict__ neigh_index,
    float* __restrict__ out,
    int B)
{
    __shared__ float sparams[TABSZ];
    for (int i = threadIdx.x; i < TABSZ; i += 256)
        sparams[i] = params[i];
    __syncthreads();

    const float2* sp2 = (const float2*)sparams;

    int t = blockIdx.x * 256 + threadIdx.x;
    int nThreads = (B + 3) >> 2;
    if (t >= nThreads) return;
    int b0 = t * 4;

    const float4* pll4 = (const float4*)pixel_latlon;   // 2 pixels per float4
    const float4* nll4 = (const float4*)neigh_latlon;
    const int4*   pix4 = (const int4*)pixel_index;
    const int4*   nix4 = (const int4*)neigh_index;

    if (b0 + 3 < B) {
        float res[4][8];

        #pragma unroll
        for (int l = 0; l < NLEV; ++l) {
            const int lbase = l * MAXSZ;
            int4   pi = pix4[(l * B) / 4 + t];
            float4 pa = pll4[(l * B) / 2 + 2 * t];       // (th0,ph0,th1,ph1)
            float4 pb = pll4[(l * B) / 2 + 2 * t + 1];   // (th2,ph2,th3,ph3)

            float a00 = 0.f, a01 = 0.f, a10 = 0.f, a11 = 0.f;
            float a20 = 0.f, a21 = 0.f, a30 = 0.f, a31 = 0.f;

            #pragma unroll
            for (int j = 0; j < 8; ++j) {
                const int sbase = (l * 8 + j) * B;
                int4   ni = nix4[sbase / 4 + t];
                float4 na = nll4[sbase / 2 + 2 * t];
                float4 nb = nll4[sbase / 2 + 2 * t + 1];
                accum_one(sp2, lbase, ni.x, na.x, na.y, pa.x, pa.y, a00, a01);
                accum_one(sp2, lbase, ni.y, na.z, na.w, pa.z, pa.w, a10, a11);
                accum_one(sp2, lbase, ni.z, nb.x, nb.y, pb.x, pb.y, a20, a21);
                accum_one(sp2, lbase, ni.w, nb.z, nb.w, pb.z, pb.w, a30, a31);
            }

            // residual (my_reps) added after neighbor sum, like the reference
            int r0 = pi.x < 0 ? 768 : pi.x;
            int r1 = pi.y < 0 ? 768 : pi.y;
            int r2 = pi.z < 0 ? 768 : pi.z;
            int r3 = pi.w < 0 ? 768 : pi.w;
            float2 m0 = sp2[lbase + r0], m1 = sp2[lbase + r1];
            float2 m2 = sp2[lbase + r2], m3 = sp2[lbase + r3];

            res[0][l] = a00 + m0.x;  res[0][4 + l] = a01 + m0.y;
            res[1][l] = a10 + m1.x;  res[1][4 + l] = a11 + m1.y;
            res[2][l] = a20 + m2.x;  res[2][4 + l] = a21 + m2.y;
            res[3][l] = a30 + m3.x;  res[3][4 + l] = a31 + m3.y;
        }

        #pragma unroll
        for (int p = 0; p < 4; ++p) {
            float4* o = (float4*)(out + (size_t)(b0 + p) * 8);
            o[0] = make_float4(res[p][0], res[p][1], res[p][2], res[p][3]);
            o[1] = make_float4(res[p][4], res[p][5], res[p][6], res[p][7]);
        }
    } else {
        // scalar tail (B not divisible by 4)
        const float2* pll2 = (const float2*)pixel_latlon;
        const float2* nll2 = (const float2*)neigh_latlon;
        for (int b = b0; b < B; ++b) {
            float res[8];
            #pragma unroll
            for (int l = 0; l < NLEV; ++l) {
                const int lbase = l * MAXSZ;
                int pi = pixel_index[l * B + b];
                if (pi < 0) pi = 768;
                float2 pll = pll2[l * B + b];
                float a0 = 0.f, a1 = 0.f;
                #pragma unroll
                for (int j = 0; j < 8; ++j) {
                    int    ni = neigh_index[(l * 8 + j) * B + b];
                    float2 nl = nll2[(l * 8 + j) * B + b];
                    accum_one(sp2, lbase, ni, nl.x, nl.y, pll.x, pll.y, a0, a1);
                }
                float2 m = sp2[lbase + pi];
                res[l] = a0 + m.x;  res[4 + l] = a1 + m.y;
            }
            float4* o = (float4*)(out + (size_t)b * 8);
            o[0] = make_float4(res[0], res[1], res[2], res[3]);
            o[1] = make_float4(res[4], res[5], res[6], res[7]);
        }
    }
}

extern "C" void kernel_launch(void* const* d_in, const int* in_sizes, int n_in,
                              void* d_out, int out_size, void* d_ws, size_t ws_size,
                              hipStream_t stream) {
    const float* params       = (const float*)d_in[0];
    const float* pixel_latlon = (const float*)d_in[1];
    const float* neigh_latlon = (const float*)d_in[2];
    const int*   pixel_index  = (const int*)d_in[3];
    const int*   neigh_index  = (const int*)d_in[4];
    float* out = (float*)d_out;

    int B = in_sizes[3] / NLEV;          // pixel_index has 4*B elements
    int nThreads = (B + 3) / 4;
    int blocks = (nThreads + 255) / 256;
    heal_encoding_kernel<<<blocks, 256, 0, stream>>>(
        params, pixel_latlon, neigh_latlon, pixel_index, neigh_index, out, B);
}

// Round 3
// 459.568 us; speedup vs baseline: 1.0681x; 1.0518x over previous
//
#include <hip/hip_runtime.h>

// HealEncoding v3: one thread per (pixel, level). Block = 512 = 128 px x 4 levels.
// All 18 per-thread global loads are issued back-to-back with no consumer in
// between; the staging __syncthreads() drains them in ONE overlapped latency
// exposure. Post-barrier work is pure LDS+VALU. Output staged through padded
// LDS so global stores are contiguous float4.
//
// params        [4, 792, 2]  f32   (25 KB -> LDS)
// pixel_latlon  [4, B, 2]    f32
// neigh_latlon  [4, 8B, 2]   f32   (element i = j*B + b)
// pixel_index   [4, B]       i32
// neigh_index   [4, 8, B]    i32   (-1 = missing -> contributes 0)
// out           [B, 8]       f32   out[b, 4*f + l] = res[l][b][f]

#define NLEV 4
#define MAXSZ 792
#define TABSZ (NLEV * MAXSZ * 2)   // 6336 floats = 25344 B
#define PPB 128                    // pixels per block
#define OSTRIDE 12                 // padded row stride (dwords) for out-stage:
                                   // 48 B rows -> float4-aligned, odd-ish banks

__global__ __launch_bounds__(512) void heal_encoding_kernel(
    const float* __restrict__ params,
    const float* __restrict__ pixel_latlon,
    const float* __restrict__ neigh_latlon,
    const int*   __restrict__ pixel_index,
    const int*   __restrict__ neigh_index,
    float* __restrict__ out,
    int B)
{
    __shared__ float stab[TABSZ];
    __shared__ float sout[PPB * OSTRIDE];   // 6 KB

    const int tid = threadIdx.x;
    const int bl  = tid & (PPB - 1);        // pixel within block
    const int l   = tid >> 7;               // level 0..3
    const int b_raw = blockIdx.x * PPB + bl;
    const int b = min(b_raw, B - 1);        // clamp so loads are unconditional

    const float2* pll2 = (const float2*)pixel_latlon;
    const float2* nll2 = (const float2*)neigh_latlon;

    // ---- phase 1: issue ALL per-thread global loads, no consumers between ----
    int   pi  = pixel_index[l * B + b];
    float2 pll = pll2[l * B + b];
    int    ni[8];
    float2 nl[8];
    #pragma unroll
    for (int j = 0; j < 8; ++j) {
        ni[j] = neigh_index[(l * 8 + j) * B + b];
        nl[j] = nll2[(l * 8 + j) * B + b];
    }

    // ---- table staging (its barrier drains phase-1 loads too, once) ----
    {
        const float4* p4  = (const float4*)params;
        float4*       st4 = (float4*)stab;
        for (int i = tid; i < TABSZ / 4; i += 512)
            st4[i] = p4[i];
    }
    __syncthreads();

    // ---- phase 2: pure LDS + VALU ----
    const float2* sp2 = (const float2*)stab;
    const int lbase = l * MAXSZ;

    float a0 = 0.0f, a1 = 0.0f;
    #pragma unroll
    for (int j = 0; j < 8; ++j) {
        float dth = nl[j].x - pll.x;
        float dph = nl[j].y - pll.y;
        float d   = sqrtf(dth * dth + dph * dph);
        float w   = (ni[j] >= 0) ? (1.0f / d) : 0.0f;   // mask -> exactly 0
        float2 r  = sp2[lbase + (ni[j] >= 0 ? ni[j] : 0)];
        a0 += w * r.x;
        a1 += w * r.y;
    }
    // residual added after neighbor sum (reference order)
    float2 m = sp2[lbase + (pi < 0 ? 768 : pi)];
    a0 += m.x;
    a1 += m.y;

    sout[bl * OSTRIDE + l]     = a0;   // feature 0 -> columns 0..3
    sout[bl * OSTRIDE + 4 + l] = a1;   // feature 1 -> columns 4..7
    __syncthreads();

    // ---- phase 3: coalesced float4 stores (256 lanes, 2 per pixel) ----
    if (tid < 2 * PPB) {
        int px = tid >> 1;
        int h  = tid & 1;
        int bo = blockIdx.x * PPB + px;
        if (bo < B) {
            float4 v = *(const float4*)&sout[px * OSTRIDE + 4 * h];
            ((float4*)(out + (size_t)bo * 8))[h] = v;
        }
    }
}

extern "C" void kernel_launch(void* const* d_in, const int* in_sizes, int n_in,
                              void* d_out, int out_size, void* d_ws, size_t ws_size,
                              hipStream_t stream) {
    const float* params       = (const float*)d_in[0];
    const float* pixel_latlon = (const float*)d_in[1];
    const float* neigh_latlon = (const float*)d_in[2];
    const int*   pixel_index  = (const int*)d_in[3];
    const int*   neigh_index  = (const int*)d_in[4];
    float* out = (float*)d_out;

    int B = in_sizes[3] / NLEV;             // pixel_index has 4*B elements
    int blocks = (B + PPB - 1) / PPB;
    heal_encoding_kernel<<<blocks, 512, 0, stream>>>(
        params, pixel_latlon, neigh_latlon, pixel_index, neigh_index, out, B);
}